// Round 14
// baseline (35.428 us; speedup 1.0000x reference)
//
#include <hip/hip_runtime.h>

#define ALPHA 0.2f
#define BATCH 16
#define WIN 100
#define KN 128          // nodes
#define DE 200          // embed dim
#define IT 8            // i-tile per consumer block
#define LINPB 7         // producer blocks per batch (7*32=224 >= 200 d)
#define NLIN (BATCH * LINPB)   // 112
#define NATT (BATCH * 16)      // 256

typedef float v2f __attribute__((ext_vector_type(2)));

// Single dispatch, block-specialized producer/consumer pipeline.
// Blocks [0,112): produce Rt[b] (write-through agent stores), bump ctr[b].
// Blocks [112,368): compute Li locally (OVERLAPS producers), spin on ctr[b]
// (7), then e-phase/softmax/PV. 368 blocks x 1024 thr, 2 blocks/CU ->
// all co-resident -> no deadlock regardless of dispatch order.
__global__ __launch_bounds__(1024, 8) void k_gat(
    const float* __restrict__ in, const float* __restrict__ lw,
    const float* __restrict__ lb, const float* __restrict__ aw,
    float* Rt, float* __restrict__ out, unsigned int* ctr) {
  __shared__ float Lis[DE][IT];        // [d][ii], 32B rows (broadcast reads)
  __shared__ float aws[DE];
  __shared__ float part[8][IT][KN];
  __shared__ float part_r[8][KN];
  __shared__ float ats[IT][132];

  int blk = blockIdx.x, t = threadIdx.x;

  if (blk < NLIN) {
    // ---------------- producer: Rt[b][d][j], 32 d's per block ----------------
    int b = blk / LINPB, dt = blk % LINPB;
    int j = t & (KN - 1);
    int dbase = __builtin_amdgcn_readfirstlane(dt * 32 + (t >> 7) * 4);
    if (dbase < DE) {
      const float* inb = in + (size_t)b * WIN * KN + j;
      const float* lwr = lw + WIN * DE + dbase;
      float ra0 = 0, ra1 = 0, ra2 = 0, ra3 = 0;
#pragma unroll 10
      for (int w = 0; w < WIN; ++w) {
        float x = inb[w * KN];
        float4 wr = *reinterpret_cast<const float4*>(lwr + w * DE);
        ra0 = fmaf(x, wr.x, ra0); ra1 = fmaf(x, wr.y, ra1);
        ra2 = fmaf(x, wr.z, ra2); ra3 = fmaf(x, wr.w, ra3);
      }
      float4 bb = *reinterpret_cast<const float4*>(lb + dbase);
      float* rp = Rt + ((size_t)b * DE + dbase) * KN + j;
      // agent-scope stores: visible at the coherence point (cross-XCD safe)
      __hip_atomic_store(rp + 0 * KN, ra0 + bb.x, __ATOMIC_RELAXED, __HIP_MEMORY_SCOPE_AGENT);
      __hip_atomic_store(rp + 1 * KN, ra1 + bb.y, __ATOMIC_RELAXED, __HIP_MEMORY_SCOPE_AGENT);
      __hip_atomic_store(rp + 2 * KN, ra2 + bb.z, __ATOMIC_RELAXED, __HIP_MEMORY_SCOPE_AGENT);
      __hip_atomic_store(rp + 3 * KN, ra3 + bb.w, __ATOMIC_RELAXED, __HIP_MEMORY_SCOPE_AGENT);
    }
    __syncthreads();                   // drains every wave's stores (vmcnt 0)
    if (t == 0)
      __hip_atomic_fetch_add(&ctr[b], 1u, __ATOMIC_RELEASE, __HIP_MEMORY_SCOPE_AGENT);
    return;
  }

  // ---------------- consumer: (b, 8-i tile) ----------------
  int ablk = blk - NLIN;
  int b = ablk >> 4, it = ablk & 15;
  int i0 = it * IT;

  // Li for this block's 8 i's — overlaps producer execution
  for (int idx = t; idx < IT * DE; idx += 1024) {
    int ii = idx / DE;                 // consecutive idx -> consecutive d
    int d = idx - ii * DE;
    const float* xc = in + (size_t)b * WIN * KN + i0 + ii;
    const float* lc = lw + d;
    float a = 0.f;
#pragma unroll 4
    for (int w = 0; w < WIN; ++w)
      a = fmaf(xc[w * KN], lc[w * DE], a);
    Lis[d][ii] = a;
  }
  if (t >= 1024 - DE) aws[t - (1024 - DE)] = aw[t - (1024 - DE)];
  __syncthreads();

  // wait for this batch's 7 producer blocks (t0 spins, others park at barrier)
  if (t == 0) {
    while (__hip_atomic_load(&ctr[b], __ATOMIC_RELAXED, __HIP_MEMORY_SCOPE_AGENT) < LINPB)
      __builtin_amdgcn_s_sleep(4);
  }
  __syncthreads();

  // e-phase: thread (j, dh) covers 25 d's for 8 i's (round-12 proven body)
  {
    int j = t & (KN - 1);
    int dh = t >> 7;
    int db = __builtin_amdgcn_readfirstlane(dh * 25);
    const float* rtb = Rt + (size_t)b * DE * KN + j;
    v2f acc0 = 0.f, acc1 = 0.f, acc2 = 0.f, acc3 = 0.f;
    float racc = 0.f;
#pragma unroll 5
    for (int dd = 0; dd < 25; ++dd) {
      int d = db + dd;
      float r = rtb[(size_t)d * KN];
      float a = aws[d];                // uniform addr -> LDS broadcast
      float4 L0 = *reinterpret_cast<const float4*>(&Lis[d][0]);
      float4 L1 = *reinterpret_cast<const float4*>(&Lis[d][4]);
      racc = fmaf(r, a, racc);
      v2f rv = {r, r}, av = {a, a}, z = 0.f;
      v2f p0 = (v2f){L0.x, L0.y} + rv;
      v2f p1 = (v2f){L0.z, L0.w} + rv;
      v2f p2 = (v2f){L1.x, L1.y} + rv;
      v2f p3 = (v2f){L1.z, L1.w} + rv;
      p0 = __builtin_elementwise_min(p0, z);
      p1 = __builtin_elementwise_min(p1, z);
      p2 = __builtin_elementwise_min(p2, z);
      p3 = __builtin_elementwise_min(p3, z);
      acc0 += p0 * av; acc1 += p1 * av; acc2 += p2 * av; acc3 += p3 * av;
    }
    part[dh][0][j] = acc0.x; part[dh][1][j] = acc0.y;
    part[dh][2][j] = acc1.x; part[dh][3][j] = acc1.y;
    part[dh][4][j] = acc2.x; part[dh][5][j] = acc2.y;
    part[dh][6][j] = acc3.x; part[dh][7][j] = acc3.y;
    part_r[dh][j] = racc;
  }
  __syncthreads();

  // softmax: wave r (r<8) owns row r; e = ra - 0.8*M (shift-invariant;
  // the j-invariant sum_d Li*aw term is dropped -> softmax unchanged)
  {
    int wid = t >> 6;
    if (wid < IT) {
      int r = wid, l = t & 63;
      float ra0 = 0.f, ra1 = 0.f, m0 = 0.f, m1 = 0.f;
#pragma unroll
      for (int s = 0; s < 8; ++s) {
        ra0 += part_r[s][l];     ra1 += part_r[s][l + 64];
        m0  += part[s][r][l];    m1  += part[s][r][l + 64];
      }
      float e0 = fmaf(m0, -(1.f - ALPHA), ra0);
      float e1 = fmaf(m1, -(1.f - ALPHA), ra1);
      float m = fmaxf(e0, e1);
      for (int off = 32; off; off >>= 1) m = fmaxf(m, __shfl_xor(m, off));
      float p0 = __expf(e0 - m), p1 = __expf(e1 - m);
      float s2 = p0 + p1;
      for (int off = 32; off; off >>= 1) s2 += __shfl_xor(s2, off);
      float inv = 1.f / s2;
      ats[r][l] = p0 * inv;
      ats[r][l + 64] = p1 * inv;
    }
  }
  __syncthreads();

  // PV: thread (w, q<8): out[b][w][i0+q]; x rows from global (L1-shared)
  if (t < 8 * WIN) {
    int w = t >> 3, q = t & 7;
    const float* xw = in + ((size_t)b * WIN + w) * KN;
    const float* ap = &ats[q][0];
    float s = 0.f;
#pragma unroll 8
    for (int jj = 0; jj < KN; jj += 4) {
      float4 x4 = *reinterpret_cast<const float4*>(xw + jj);
      float4 aa = *reinterpret_cast<const float4*>(ap + jj);
      s = fmaf(aa.x, x4.x, s); s = fmaf(aa.y, x4.y, s);
      s = fmaf(aa.z, x4.z, s); s = fmaf(aa.w, x4.w, s);
    }
    out[((size_t)b * WIN + w) * KN + i0 + q] = 1.f / (1.f + __expf(-s));
  }
}

extern "C" void kernel_launch(void* const* d_in, const int* in_sizes, int n_in,
                              void* d_out, int out_size, void* d_ws, size_t ws_size,
                              hipStream_t stream) {
  const float* in = (const float*)d_in[0];   // (16,100,128)
  const float* lw = (const float*)d_in[1];   // (200,200)
  const float* lb = (const float*)d_in[2];   // (200,)
  const float* aw = (const float*)d_in[3];   // (200,)
  float* out = (float*)d_out;                // (16,100,128)

  float* Rt = (float*)d_ws;                  // 16*200*128 floats (1.6 MB)
  unsigned int* ctr =
      (unsigned int*)((char*)d_ws + (size_t)BATCH * DE * KN * sizeof(float));

  hipMemsetAsync(ctr, 0, BATCH * sizeof(unsigned int), stream);  // graph-safe
  k_gat<<<NLIN + NATT, 1024, 0, stream>>>(in, lw, lb, aw, Rt, out, ctr);
}

// Round 15
// 27.442 us; speedup vs baseline: 1.2910x; 1.2910x over previous
//
#include <hip/hip_runtime.h>

#define ALPHA 0.2f
#define BATCH 16
#define WIN 100
#define KN 128          // nodes
#define DE 200          // embed dim
#define IT 8            // i-tile per k_attn block
#define NQ 50           // d-quads (200/4)

typedef float v2f __attribute__((ext_vector_type(2)));

// Kernel A (round-7 structure): grid 16b x 25dt, 256 thr, zero LDS.
// lane j = t&127, d-quad = dt*8 + (t>>7)*4 (weights via scalar path).
// NEW: Rt stored quad-packed  Rt[b][dq][j][4]  -> one coalesced float4 store
// per thread, and the consumer gets 4 d's per VMEM load.
//   Rt[b][dq][j][k] = sum_w x[w][j]*lw[100+w][4dq+k] + lb[4dq+k]
//   Lt[b][d][j]     = sum_w x[w][j]*lw[w][d]          (unchanged layout)
__global__ __launch_bounds__(256) void k_lin(
    const float* __restrict__ in, const float* __restrict__ lw,
    const float* __restrict__ lb, float* __restrict__ Rt, float* __restrict__ Lt) {
  int blk = blockIdx.x;
  int b = blk / 25, dt = blk % 25;
  int t = threadIdx.x;
  int j = t & (KN - 1);
  int dbase = __builtin_amdgcn_readfirstlane(dt * 8 + (t >> 7) * 4);
  const float* inb = in + (size_t)b * WIN * KN + j;
  const float* lwl = lw + dbase;
  const float* lwr = lw + WIN * DE + dbase;
  float la0 = 0, la1 = 0, la2 = 0, la3 = 0;
  float ra0 = 0, ra1 = 0, ra2 = 0, ra3 = 0;
#pragma unroll 10
  for (int w = 0; w < WIN; ++w) {
    float x = inb[w * KN];
    float4 wl = *reinterpret_cast<const float4*>(lwl + w * DE);
    float4 wr = *reinterpret_cast<const float4*>(lwr + w * DE);
    la0 = fmaf(x, wl.x, la0); la1 = fmaf(x, wl.y, la1);
    la2 = fmaf(x, wl.z, la2); la3 = fmaf(x, wl.w, la3);
    ra0 = fmaf(x, wr.x, ra0); ra1 = fmaf(x, wr.y, ra1);
    ra2 = fmaf(x, wr.z, ra2); ra3 = fmaf(x, wr.w, ra3);
  }
  float4 bb = *reinterpret_cast<const float4*>(lb + dbase);
  float4* rq = reinterpret_cast<float4*>(Rt) +
               ((size_t)b * NQ + (dbase >> 2)) * KN + j;
  *rq = make_float4(ra0 + bb.x, ra1 + bb.y, ra2 + bb.z, ra3 + bb.w);
  float* lp = Lt + ((size_t)b * DE + dbase) * KN + j;
  lp[0 * KN] = la0; lp[1 * KN] = la1; lp[2 * KN] = la2; lp[3 * KN] = la3;
}

// Kernel B (round-7 structure): per (b, 8-i tile), 1024 thr.
// e-phase: thread (j, dh) covers quads q ≡ dh (mod 8), 4 d's per float4 VMEM.
//   M[ii][j] = sum_d min(Lt[d][i0+ii]+Rt[d][j],0)*aw[d]; ra[j] = sum_d Rt*aw
//   e = ra - 0.8*M (j-invariant per-i shift dropped; softmax unchanged)
__global__ __launch_bounds__(1024) void k_attn_out(
    const float* __restrict__ in, const float* __restrict__ aw,
    const float* __restrict__ Rt, const float* __restrict__ Lt,
    float* __restrict__ out) {
  int blk = blockIdx.x;
  int b = blk >> 4, it = blk & 15;
  int i0 = it * IT;
  int t = threadIdx.x;
  __shared__ float part[8][IT][KN];
  __shared__ float part_r[8][KN];
  __shared__ float ats[IT][132];

  // e-phase
  {
    int j = t & (KN - 1);
    int dh = t >> 7;
    const float4* rtq = reinterpret_cast<const float4*>(Rt) +
                        (size_t)b * NQ * KN + j;
    const float* ltb = Lt + (size_t)b * DE * KN + i0;   // lane-invariant -> s_load
    v2f acc0 = 0.f, acc1 = 0.f, acc2 = 0.f, acc3 = 0.f;
    float racc = 0.f;

#define EDOT(rr, aa, dd)                                                     \
    {                                                                        \
      float4 L0 = *reinterpret_cast<const float4*>(ltb + (size_t)(dd) * KN); \
      float4 L1 = *reinterpret_cast<const float4*>(ltb + (size_t)(dd) * KN + 4); \
      racc = fmaf((rr), (aa), racc);                                         \
      v2f rv = {(rr), (rr)}, av = {(aa), (aa)}, z = 0.f;                     \
      v2f p0 = (v2f){L0.x, L0.y} + rv;                                       \
      v2f p1 = (v2f){L0.z, L0.w} + rv;                                       \
      v2f p2 = (v2f){L1.x, L1.y} + rv;                                       \
      v2f p3 = (v2f){L1.z, L1.w} + rv;                                       \
      p0 = __builtin_elementwise_min(p0, z);                                 \
      p1 = __builtin_elementwise_min(p1, z);                                 \
      p2 = __builtin_elementwise_min(p2, z);                                 \
      p3 = __builtin_elementwise_min(p3, z);                                 \
      acc0 += p0 * av; acc1 += p1 * av; acc2 += p2 * av; acc3 += p3 * av;    \
    }

#pragma unroll 2
    for (int q = dh; q < NQ; q += 8) {
      float4 r4 = rtq[(size_t)q * KN];                  // 4 d's, 1 KB/wave
      float4 a4 = *reinterpret_cast<const float4*>(aw + q * 4);  // uniform
      int d0 = q * 4;
      EDOT(r4.x, a4.x, d0 + 0)
      EDOT(r4.y, a4.y, d0 + 1)
      EDOT(r4.z, a4.z, d0 + 2)
      EDOT(r4.w, a4.w, d0 + 3)
    }
#undef EDOT

    part[dh][0][j] = acc0.x; part[dh][1][j] = acc0.y;
    part[dh][2][j] = acc1.x; part[dh][3][j] = acc1.y;
    part[dh][4][j] = acc2.x; part[dh][5][j] = acc2.y;
    part[dh][6][j] = acc3.x; part[dh][7][j] = acc3.y;
    part_r[dh][j] = racc;
  }
  __syncthreads();

  // softmax: wave r (r<8) owns row r; lanes l and l+64
  {
    int wid = t >> 6;
    if (wid < IT) {
      int r = wid, l = t & 63;
      float ra0 = 0.f, ra1 = 0.f, m0 = 0.f, m1 = 0.f;
#pragma unroll
      for (int s = 0; s < 8; ++s) {
        ra0 += part_r[s][l];     ra1 += part_r[s][l + 64];
        m0  += part[s][r][l];    m1  += part[s][r][l + 64];
      }
      float e0 = fmaf(m0, -(1.f - ALPHA), ra0);
      float e1 = fmaf(m1, -(1.f - ALPHA), ra1);
      float m = fmaxf(e0, e1);
      for (int off = 32; off; off >>= 1) m = fmaxf(m, __shfl_xor(m, off));
      float p0 = __expf(e0 - m), p1 = __expf(e1 - m);
      float s2 = p0 + p1;
      for (int off = 32; off; off >>= 1) s2 += __shfl_xor(s2, off);
      float inv = 1.f / s2;
      ats[r][l] = p0 * inv;
      ats[r][l + 64] = p1 * inv;
    }
  }
  __syncthreads();

  // PV: thread (w, q<8): out[b][w][i0+q]; x rows from global (L1-shared)
  if (t < 8 * WIN) {
    int w = t >> 3, q = t & 7;
    const float* xw = in + ((size_t)b * WIN + w) * KN;
    const float* ap = &ats[q][0];
    float s = 0.f;
#pragma unroll 8
    for (int jj = 0; jj < KN; jj += 4) {
      float4 x4 = *reinterpret_cast<const float4*>(xw + jj);
      float4 aa = *reinterpret_cast<const float4*>(ap + jj);
      s = fmaf(aa.x, x4.x, s); s = fmaf(aa.y, x4.y, s);
      s = fmaf(aa.z, x4.z, s); s = fmaf(aa.w, x4.w, s);
    }
    out[((size_t)b * WIN + w) * KN + i0 + q] = 1.f / (1.f + __expf(-s));
  }
}

extern "C" void kernel_launch(void* const* d_in, const int* in_sizes, int n_in,
                              void* d_out, int out_size, void* d_ws, size_t ws_size,
                              hipStream_t stream) {
  const float* in = (const float*)d_in[0];   // (16,100,128)
  const float* lw = (const float*)d_in[1];   // (200,200)
  const float* lb = (const float*)d_in[2];   // (200,)
  const float* aw = (const float*)d_in[3];   // (200,)
  float* out = (float*)d_out;                // (16,100,128)

  float* Rt = (float*)d_ws;                          // quad-packed, 1.6 MB
  float* Lt = Rt + (size_t)BATCH * DE * KN;          // 1.6 MB

  k_lin     <<<BATCH * 25, 256, 0, stream>>>(in, lw, lb, Rt, Lt);
  k_attn_out<<<BATCH * 16, 1024, 0, stream>>>(in, aw, Rt, Lt, out);
}